// Round 7
// baseline (214.160 us; speedup 1.0000x reference)
//
#include <hip/hip_runtime.h>
#include <cstdint>

#define EPSN 1e-12f
static constexpr int B_ROWS = 1024;
static constexpr int IN_DIM = 512;
static constexpr int OUT_DIM = 64000;

typedef __attribute__((ext_vector_type(8))) short bf16x8;
typedef __attribute__((ext_vector_type(4))) float f32x4;

__device__ __forceinline__ unsigned short f2bf(float f) {
  uint32_t u = __builtin_bit_cast(uint32_t, f);
  u += 0x7fffu + ((u >> 16) & 1u);   // round-to-nearest-even
  return (unsigned short)(u >> 16);
}

__device__ __forceinline__ float bf2f(unsigned short h) {
  uint32_t u = (uint32_t)h << 16;
  return __builtin_bit_cast(float, u);
}

__device__ __forceinline__ float wave_sum(float v) {
#pragma unroll
  for (int off = 32; off; off >>= 1) v += __shfl_xor(v, off);
  return v;
}

__device__ __forceinline__ void async16(const void* g, void* l) {
  __builtin_amdgcn_global_load_lds((const __attribute__((address_space(1))) uint32_t*)g,
                                   (__attribute__((address_space(3))) uint32_t*)l, 16, 0, 0);
}

// --- kernel 1: x-prep (norms + bf16 cast) + exact fixdot from RAW W ---
__global__ void prep_kernel(const float* __restrict__ X, const int* __restrict__ label,
                            const float* __restrict__ Wg, float* __restrict__ norms,
                            float* __restrict__ fixdot, unsigned short* __restrict__ xbf) {
  int lane = threadIdx.x & 63;
  int row = blockIdx.x * 4 + (threadIdx.x >> 6);
  const float* src = X + (size_t)row * IN_DIM + lane * 8;
  float4 a = *(const float4*)src;
  float4 b = *(const float4*)(src + 4);
  uint4 u;
  u.x = (uint32_t)f2bf(a.x) | ((uint32_t)f2bf(a.y) << 16);
  u.y = (uint32_t)f2bf(a.z) | ((uint32_t)f2bf(a.w) << 16);
  u.z = (uint32_t)f2bf(b.x) | ((uint32_t)f2bf(b.y) << 16);
  u.w = (uint32_t)f2bf(b.z) | ((uint32_t)f2bf(b.w) << 16);
  *(uint4*)(xbf + (size_t)row * IN_DIM + lane * 8) = u;
  float ssx = a.x * a.x;
  ssx = fmaf(a.y, a.y, ssx); ssx = fmaf(a.z, a.z, ssx); ssx = fmaf(a.w, a.w, ssx);
  ssx = fmaf(b.x, b.x, ssx); ssx = fmaf(b.y, b.y, ssx); ssx = fmaf(b.z, b.z, ssx);
  ssx = fmaf(b.w, b.w, ssx);
  int lab = label[row];
  const float* wsrc = Wg + (size_t)lab * IN_DIM + lane * 8;
  float4 wa = *(const float4*)wsrc, wb = *(const float4*)(wsrc + 4);
  float d = a.x * wa.x;
  d = fmaf(a.y, wa.y, d); d = fmaf(a.z, wa.z, d); d = fmaf(a.w, wa.w, d);
  d = fmaf(b.x, wb.x, d); d = fmaf(b.y, wb.y, d); d = fmaf(b.z, wb.z, d);
  d = fmaf(b.w, wb.w, d);
  float ssw = wa.x * wa.x;
  ssw = fmaf(wa.y, wa.y, ssw); ssw = fmaf(wa.z, wa.z, ssw); ssw = fmaf(wa.w, wa.w, ssw);
  ssw = fmaf(wb.x, wb.x, ssw); ssw = fmaf(wb.y, wb.y, ssw); ssw = fmaf(wb.z, wb.z, ssw);
  ssw = fmaf(wb.w, wb.w, ssw);
  ssx = wave_sum(ssx);
  d = wave_sum(d);
  ssw = wave_sum(ssw);
  if (lane == 0) {
    norms[row] = sqrtf(ssx);
    fixdot[row] = d / fmaxf(sqrtf(ssw), EPSN);   // = x . wn[lab], exact f32
  }
}

// --- kernel 2: W -> normalized bf16 (wbf) only; wn f32 written by GEMM epilogue ---
__global__ void wcast_kernel(const float* __restrict__ Wg, unsigned short* __restrict__ wbf) {
  int lane = threadIdx.x & 63;
  int row = blockIdx.x * 4 + (threadIdx.x >> 6);
  const float* src = Wg + (size_t)row * IN_DIM + lane * 8;
  float4 a = *(const float4*)src;
  float4 b = *(const float4*)(src + 4);
  float ss = a.x * a.x;
  ss = fmaf(a.y, a.y, ss); ss = fmaf(a.z, a.z, ss); ss = fmaf(a.w, a.w, ss);
  ss = fmaf(b.x, b.x, ss); ss = fmaf(b.y, b.y, ss); ss = fmaf(b.z, b.z, ss);
  ss = fmaf(b.w, b.w, ss);
  ss = wave_sum(ss);
  float inv = 1.0f / fmaxf(sqrtf(ss), EPSN);
  uint4 u;
  u.x = (uint32_t)f2bf(a.x * inv) | ((uint32_t)f2bf(a.y * inv) << 16);
  u.y = (uint32_t)f2bf(a.z * inv) | ((uint32_t)f2bf(a.w * inv) << 16);
  u.z = (uint32_t)f2bf(b.x * inv) | ((uint32_t)f2bf(b.y * inv) << 16);
  u.w = (uint32_t)f2bf(b.z * inv) | ((uint32_t)f2bf(b.w * inv) << 16);
  *(uint4*)(wbf + (size_t)row * IN_DIM + lane * 8) = u;
}

// --- kernel 3: bf16 MFMA GEMM (M=1024,N=64000,K=512) + margin epilogue + wn write ---
// BM=256, BN=128, BK=32; 4 waves (2Mx2N), wave-tile 128x64 (acc[8][4], 32 MFMA
// per phase at 0.375 KB LDS-read/MFMA). Ring-3 LDS = 3 x (A 16K + B 8K) = 72 KiB
// -> 2 blocks/CU (epilogue/prologue/LDS-HBM overlap across blocks).
// Single barrier per phase: {vmcnt(6|0) -> barrier -> issue sub sig+2 into slot
// (sig+2)%3 = (sig-1)%3 (whose readers drained before this barrier) -> ds_read
// slot sig%3 -> MFMA}. Counted vmcnt: 6 gloads/thread/sub; depth-2 ring.
__global__ __launch_bounds__(256, 2) void gemm_epi_kernel(
    const unsigned short* __restrict__ Abf, const unsigned short* __restrict__ Bbf,
    const float* __restrict__ norms, const float* __restrict__ fixdot,
    const int* __restrict__ label, const float* __restrict__ mArr,
    float* __restrict__ out0, float* __restrict__ wnOut) {
  __shared__ char smem[73728];   // slot s @ s*24576; A @ +0 (16K), B @ +16384 (8K)

  const int t = threadIdx.x;
  int flat = blockIdx.x;          // 2000 = 8 * 250, bijective XCD swizzle
  int xcd = flat & 7;
  int wk = (flat >> 3) + xcd * 250;
  int mT = wk & 3, nT = wk >> 2;  // 4 mT siblings per nT consecutive on one XCD
  int rowA0 = mT * 256, rowB0 = nT * 128;

  int lane = t & 63;
  int wid = t >> 6;
  int wm = wid >> 1, wn2 = wid & 1;   // 2M x 2N wave grid
  int rl = lane & 15, sl = lane >> 4;

  // staging chunk map (inverse swizzle): chunk c -> row r = c>>2, 16B-slot q
  // A: 1024 chunks (4/thread), B: 512 chunks (2/thread)
  const unsigned short* aP[4];
  const unsigned short* bP[2];
#pragma unroll
  for (int c = 0; c < 4; ++c) {
    int ch = t + c * 256;
    int r = ch >> 2, q = (ch & 3) ^ ((r >> 1) & 3);
    aP[c] = Abf + (size_t)(rowA0 + r) * IN_DIM + q * 8;
  }
#pragma unroll
  for (int c = 0; c < 2; ++c) {
    int ch = t + c * 256;
    int r = ch >> 2, q = (ch & 3) ^ ((r >> 1) & 3);
    bP[c] = Bbf + (size_t)(rowB0 + r) * IN_DIM + q * 8;
  }

  auto issueSub = [&](int sig, int slot) {
    int kcol = sig * 32;
    char* aD = smem + slot * 24576;
    char* bD = aD + 16384;
#pragma unroll
    for (int c = 0; c < 4; ++c) async16(aP[c] + kcol, aD + (t + c * 256) * 16);
#pragma unroll
    for (int c = 0; c < 2; ++c) async16(bP[c] + kcol, bD + (t + c * 256) * 16);
  };

  issueSub(0, 0); issueSub(1, 1);   // depth-2 prologue (12 gloads/thread)

  f32x4 acc[8][4];
#pragma unroll
  for (int m = 0; m < 8; ++m)
#pragma unroll
    for (int n = 0; n < 4; ++n) acc[m][n] = (f32x4){0.f, 0.f, 0.f, 0.f};

  int slotR = 0, slotW = 2;
#pragma unroll 1
  for (int sigma = 0; sigma < 16; ++sigma) {
    __builtin_amdgcn_sched_barrier(0);
    if (sigma <= 14) asm volatile("s_waitcnt vmcnt(6)" ::: "memory");
    else             asm volatile("s_waitcnt vmcnt(0)" ::: "memory");
    __builtin_amdgcn_s_barrier();
    __builtin_amdgcn_sched_barrier(0);
    if (sigma <= 13) issueSub(sigma + 2, slotW);  // slot (sigma-1)%3: readers drained

    const char* aB = smem + slotR * 24576;
    const char* bB = aB + 16384;
    bf16x8 av[8], bv[4];
#pragma unroll
    for (int m = 0; m < 8; ++m) {
      int r = wm * 128 + m * 16 + rl;
      av[m] = *(const bf16x8*)(aB + r * 64 + ((sl ^ ((r >> 1) & 3)) * 16));
    }
#pragma unroll
    for (int n = 0; n < 4; ++n) {
      int r = wn2 * 64 + n * 16 + rl;
      bv[n] = *(const bf16x8*)(bB + r * 64 + ((sl ^ ((r >> 1) & 3)) * 16));
    }
    __builtin_amdgcn_s_setprio(1);
#pragma unroll
    for (int n = 0; n < 4; ++n)
#pragma unroll
      for (int m = 0; m < 8; ++m)
        acc[m][n] = __builtin_amdgcn_mfma_f32_16x16x32_bf16(av[m], bv[n], acc[m][n], 0, 0, 0);
    __builtin_amdgcn_s_setprio(0);
    slotR = (slotR == 2) ? 0 : slotR + 1;
    slotW = (slotW == 2) ? 0 : slotW + 1;
  }

  // ---- wn f32 output: this mT-sibling writes 32 rows of nT-panel from L2-hot
  // wbf (bf16-rounded; error << threshold). 256 thr: row t>>3, 64-f32 chunk t&7.
  {
    int r = t >> 3;                      // 0..31
    int c0 = (t & 7) * 64;
    int row = rowB0 + mT * 32 + r;
    const unsigned short* srcp = Bbf + (size_t)row * IN_DIM + c0;
    float* dst = wnOut + (size_t)row * IN_DIM + c0;
#pragma unroll
    for (int g = 0; g < 8; ++g) {
      uint4 uu = *(const uint4*)(srcp + g * 8);
      float4 f;
      f.x = bf2f((unsigned short)(uu.x & 0xffff)); f.y = bf2f((unsigned short)(uu.x >> 16));
      f.z = bf2f((unsigned short)(uu.y & 0xffff)); f.w = bf2f((unsigned short)(uu.y >> 16));
      *(float4*)(dst + g * 8) = f;
      f.x = bf2f((unsigned short)(uu.z & 0xffff)); f.y = bf2f((unsigned short)(uu.z >> 16));
      f.z = bf2f((unsigned short)(uu.w & 0xffff)); f.w = bf2f((unsigned short)(uu.w >> 16));
      *(float4*)(dst + g * 8 + 4) = f;
    }
  }

  // ---- margin epilogue: out = rawdot except at (r, label[r]) ----
  float mm = mArr[0];
  float cm = cosf(mm), sm = sinf(mm);
  int rowb = rowA0 + wm * 128, colb = rowB0 + wn2 * 64;
#pragma unroll
  for (int m = 0; m < 8; ++m) {
#pragma unroll
    for (int q = 0; q < 4; ++q) {
      int R = rowb + m * 16 + sl * 4 + q;
      int lab = label[R];
      float nv = norms[R], fv = fixdot[R];
      float* orow = out0 + (size_t)R * OUT_DIM;
#pragma unroll
      for (int n = 0; n < 4; ++n) {
        int Cc = colb + n * 16 + rl;
        float val = acc[m][n][q];
        if (Cc == lab) {
          float c = fv / fmaxf(nv, EPSN);
          val = (c > 0.f) ? nv * (c * cm - sqrtf(fmaxf(1.f - c * c, 0.f)) * sm) : fv;
        }
        orow[Cc] = val;
      }
    }
  }
}

extern "C" void kernel_launch(void* const* d_in, const int* in_sizes, int n_in,
                              void* d_out, int out_size, void* d_ws, size_t ws_size,
                              hipStream_t stream) {
  const float* x = (const float*)d_in[0];
  const int* label = (const int*)d_in[1];
  const float* weight = (const float*)d_in[2];
  const float* mArr = (const float*)d_in[4];  // d_in[3] = s, unused by normfree output

  float* out0 = (float*)d_out;                               // [1024, 64000]
  float* wnOut = out0 + (size_t)B_ROWS * OUT_DIM;            // [64000, 512]

  char* ws = (char*)d_ws;
  float* norms = (float*)ws;                                 // 4 KiB
  float* fixdot = (float*)(ws + 4096);                       // 4 KiB
  unsigned short* xbf = (unsigned short*)(ws + 8192);        // 1 MiB
  unsigned short* wbf = (unsigned short*)(ws + 8192 + 2ull * B_ROWS * IN_DIM);  // 65.5 MiB

  prep_kernel<<<B_ROWS / 4, 256, 0, stream>>>(x, label, weight, norms, fixdot, xbf);
  wcast_kernel<<<OUT_DIM / 4, 256, 0, stream>>>(weight, wbf);
  gemm_epi_kernel<<<2000, 256, 0, stream>>>(xbf, wbf, norms, fixdot, label, mArr,
                                            out0, wnOut);
}